// Round 1
// baseline (1453.464 us; speedup 1.0000x reference)
//
#include <hip/hip_runtime.h>
#include <stdint.h>

#define CDIV(a,b) (((a)+(b)-1)/(b))

typedef unsigned short u16;
using bf16x8  = __attribute__((ext_vector_type(8))) short;
using floatx4 = __attribute__((ext_vector_type(4))) float;

constexpr int B_N   = 2048;   // batch
constexpr int IN_N  = 784;
constexpr int H_N   = 512;
constexpr int OUT_N = 512;
constexpr int E_N   = 8;
constexpr int ER_N  = 4;      // recurrent experts
constexpr int ES_N  = 4;      // simple experts
constexpr int T_N   = 28;
constexpr int F_N   = 28;
constexpr int G4H   = 2048;   // 4*H
constexpr int KA    = 544;    // 512 (h) + 28 (x_t) + 4 pad  -> mult of 32
constexpr int XP    = 800;    // 784 padded to mult of 32

__device__ __forceinline__ u16 f2bf(float f) {
  union { float f; uint32_t u; } v; v.f = f;
  uint32_t r = v.u + 0x7fffu + ((v.u >> 16) & 1u);   // RNE
  return (u16)(r >> 16);
}
__device__ __forceinline__ float bf2f(u16 u) {
  union { uint32_t u; float f; } v; v.u = ((uint32_t)u) << 16;
  return v.f;
}
__device__ __forceinline__ float sigm(float x)  { return 1.f / (1.f + __expf(-x)); }
__device__ __forceinline__ float tanhf_(float x){ return 1.f - 2.f / (__expf(2.f * x) + 1.f); }

// async global->LDS, 16B per lane. LDS dest = wave-uniform base + lane*16.
__device__ __forceinline__ void async16(const void* g, void* l) {
  __builtin_amdgcn_global_load_lds(
      (__attribute__((address_space(1))) void*)g,
      (__attribute__((address_space(3))) void*)l, 16, 0, 0);
}

// ---------------- GEMM: C[z] = A[z] @ B[z]^T + bias[z], optional relu, out bf16/f32 ---
// A: [M x K] rows lda (bf16), B: [N x K] rows ldb (bf16, "BT" layout), C: [M x N] rows ldc
// M = gridDim.y*128, N = gridDim.x*128. K mult of 32, lda/ldb mult of 8.
template<int RELU, int OBF>
__global__ __launch_bounds__(256, 2)
void gemm_bt(const u16* __restrict__ A, int lda, long sAz,
             const u16* __restrict__ Bw, int ldb, long sBz,
             const float* __restrict__ bias, int sBiz,
             void* __restrict__ Cv, int ldc, long sCz,
             int K)
{
  __shared__ __align__(16) u16 As[128 * 32];
  __shared__ __align__(16) u16 Bs[128 * 32];
  const int tid  = threadIdx.x;
  const int lane = tid & 63;
  const int wave = tid >> 6;
  const int m0 = blockIdx.y * 128;
  const int n0 = blockIdx.x * 128;
  const int z  = blockIdx.z;
  const u16* Ab = A  + (size_t)z * sAz;
  const u16* Bb = Bw + (size_t)z * sBz;

  const int wm   = (wave & 1) * 64;
  const int wn   = (wave >> 1) * 64;
  const int lm   = lane & 15;
  const int quad = lane >> 4;

  // staging slots: slot s (0..511) covers row s>>2, k-cols (s&3)*8..+7 (16B)
  const int s0 = wave * 64 + lane;
  const int r0 = s0 >> 2, c0 = (s0 & 3) * 8;
  const int s1 = s0 + 256;
  const int r1 = s1 >> 2, c1 = (s1 & 3) * 8;

  floatx4 acc[4][4] = {};

  for (int k0 = 0; k0 < K; k0 += 32) {
    async16(Ab + (size_t)(m0 + r0) * lda + (k0 + c0), As + wave * 512);
    async16(Ab + (size_t)(m0 + r1) * lda + (k0 + c1), As + 2048 + wave * 512);
    async16(Bb + (size_t)(n0 + r0) * ldb + (k0 + c0), Bs + wave * 512);
    async16(Bb + (size_t)(n0 + r1) * ldb + (k0 + c1), Bs + 2048 + wave * 512);
    __syncthreads();                       // drains vmcnt(0): LDS tiles ready
    bf16x8 af[4], bf_[4];
#pragma unroll
    for (int i = 0; i < 4; ++i)
      af[i] = *(const bf16x8*)&As[(wm + i * 16 + lm) * 32 + quad * 8];
#pragma unroll
    for (int j = 0; j < 4; ++j)
      bf_[j] = *(const bf16x8*)&Bs[(wn + j * 16 + lm) * 32 + quad * 8];
#pragma unroll
    for (int i = 0; i < 4; ++i)
#pragma unroll
      for (int j = 0; j < 4; ++j)
        acc[i][j] = __builtin_amdgcn_mfma_f32_16x16x32_bf16(af[i], bf_[j], acc[i][j], 0, 0, 0);
    __syncthreads();
  }

  float bj[4];
#pragma unroll
  for (int j = 0; j < 4; ++j)
    bj[j] = bias ? bias[z * sBiz + n0 + wn + j * 16 + lm] : 0.f;

  // D layout (verified m89): col = lane&15, row = quad*4 + r
#pragma unroll
  for (int i = 0; i < 4; ++i) {
#pragma unroll
    for (int r = 0; r < 4; ++r) {
      int m = m0 + wm + i * 16 + quad * 4 + r;
      size_t row = (size_t)z * sCz + (size_t)m * ldc;
#pragma unroll
      for (int j = 0; j < 4; ++j) {
        int n = n0 + wn + j * 16 + lm;
        float v = acc[i][j][r] + bj[j];
        if (RELU) v = fmaxf(v, 0.f);
        if (OBF) ((u16*)Cv)[row + n] = f2bf(v);
        else     ((float*)Cv)[row + n] = v;
      }
    }
  }
}

// ---------------- LSTM cell: reads gates [ER,B,4H] bf16, updates c (f32), h->Abuf (bf16),
// and stages x_{t+1} slice into Abuf cols [512,540).
__global__ __launch_bounds__(256)
void lstm_cell(const u16* __restrict__ G, float* __restrict__ C,
               u16* __restrict__ A, const u16* __restrict__ xb, int t)
{
  int idx = blockIdx.x * 256 + threadIdx.x;   // ER*B*H = 2^22, exact grid
  int j = idx & (H_N - 1);
  int b = (idx >> 9) & (B_N - 1);
  int e = idx >> 20;
  size_t g0 = ((size_t)(e * B_N + b)) * G4H;
  float ig = sigm (bf2f(G[g0 + j]));
  float fg = sigm (bf2f(G[g0 + H_N + j]));
  float gg = tanhf_(bf2f(G[g0 + 2 * H_N + j]));
  float og = sigm (bf2f(G[g0 + 3 * H_N + j]));
  float c = fg * C[idx] + ig * gg;
  C[idx] = c;
  float h = og * tanhf_(c);
  size_t a0 = ((size_t)(e * B_N + b)) * KA;
  A[a0 + j] = f2bf(h);
  if (j < F_N && t + 1 < T_N)
    A[a0 + H_N + j] = xb[(size_t)b * XP + (t + 1) * F_N + j];
}

// ---------------- gate: softmax(scores/e), top-5, renormalize. one wave per row. ----
__global__ __launch_bounds__(256)
void gate_k(const float* __restrict__ x, const float* __restrict__ Wg,
            const float* __restrict__ bg, float* __restrict__ Wt)
{
  int lane = threadIdx.x & 63;
  int row  = blockIdx.x * 4 + (threadIdx.x >> 6);
  float ps[E_N];
#pragma unroll
  for (int e = 0; e < E_N; ++e) ps[e] = 0.f;
  const float* xr = x + (size_t)row * IN_N;
  for (int k = lane; k < IN_N; k += 64) {
    float xv = xr[k];
#pragma unroll
    for (int e = 0; e < E_N; ++e) ps[e] += xv * Wg[e * IN_N + k];
  }
#pragma unroll
  for (int e = 0; e < E_N; ++e) {
#pragma unroll
    for (int off = 32; off >= 1; off >>= 1) ps[e] += __shfl_down(ps[e], off);
  }
  if (lane == 0) {
    float s[E_N], mx = -1e30f;
#pragma unroll
    for (int e = 0; e < E_N; ++e) { s[e] = (ps[e] + bg[e]) * 0.36787944117144233f; mx = fmaxf(mx, s[e]); }
    float pr[E_N], sum = 0.f;
#pragma unroll
    for (int e = 0; e < E_N; ++e) { pr[e] = __expf(s[e] - mx); sum += pr[e]; }
    float inv = 1.f / sum;
#pragma unroll
    for (int e = 0; e < E_N; ++e) pr[e] *= inv;
    unsigned used = 0; float wsum = 0.f;
    for (int k = 0; k < 5; ++k) {            // K = 5 active
      int am = -1; float bv = -1.f;
      for (int e = 0; e < E_N; ++e)
        if (!((used >> e) & 1) && pr[e] > bv) { bv = pr[e]; am = e; }
      used |= 1u << am; wsum += pr[am];
    }
    float winv = 1.f / (wsum + 1e-8f);
    for (int e = 0; e < E_N; ++e)
      Wt[row * E_N + e] = ((used >> e) & 1) ? pr[e] * winv : 0.f;
  }
}

// ---------------- combine: out[b,o] = sum_e w[b,e]*O[e,b,o] ----
__global__ __launch_bounds__(256)
void combine_k(const float* __restrict__ O, const float* __restrict__ Wt, float* __restrict__ out)
{
  int idx = blockIdx.x * 256 + threadIdx.x;
  if (idx >= B_N * OUT_N) return;
  int b = idx / OUT_N;
  float a = 0.f;
#pragma unroll
  for (int e = 0; e < E_N; ++e)
    a += Wt[b * E_N + e] * O[(size_t)e * B_N * OUT_N + idx];
  out[idx] = a;
}

// ---------------- prep kernels ----
__global__ void prep_x_k(const float* __restrict__ x, u16* __restrict__ xb) {
  int idx = blockIdx.x * 256 + threadIdx.x;
  if (idx >= B_N * XP) return;
  int k = idx % XP, b = idx / XP;
  xb[idx] = f2bf(k < IN_N ? x[(size_t)b * IN_N + k] : 0.f);
}
__global__ void prep_wcat_k(const float* __restrict__ Whh, const float* __restrict__ Wih,
                            u16* __restrict__ Wc) {
  int idx = blockIdx.x * 256 + threadIdx.x;
  if (idx >= ER_N * G4H * KA) return;
  int c = idx % KA; int g = (idx / KA) % G4H; int e = idx / (KA * G4H);
  float v = 0.f;
  if (c < H_N)             v = Whh[((size_t)(e * G4H + g)) * H_N + c];
  else if (c < H_N + F_N)  v = Wih[((size_t)(e * G4H + g)) * F_N + (c - H_N)];
  Wc[idx] = f2bf(v);
}
__global__ void prep_brec_k(const float* a, const float* b, float* o) {
  int idx = blockIdx.x * 256 + threadIdx.x;
  if (idx < ER_N * G4H) o[idx] = a[idx] + b[idx];
}
__global__ void cvt_k(const float* __restrict__ in, u16* __restrict__ o, int n) {
  int idx = blockIdx.x * 256 + threadIdx.x;
  if (idx < n) o[idx] = f2bf(in[idx]);
}
__global__ void prep_w1_k(const float* __restrict__ W1, u16* __restrict__ o) {
  int idx = blockIdx.x * 256 + threadIdx.x;
  if (idx >= ES_N * H_N * XP) return;
  int k = idx % XP; int r = idx / XP;
  o[idx] = f2bf(k < IN_N ? W1[(size_t)r * IN_N + k] : 0.f);
}
__global__ void init_A_k(u16* __restrict__ A, const u16* __restrict__ xb) {
  int idx = blockIdx.x * 256 + threadIdx.x;
  if (idx >= ER_N * B_N * KA) return;
  int c = idx % KA; int b = (idx / KA) % B_N;
  u16 v = 0;                                  // h0 = 0, pad = 0
  if (c >= H_N && c < H_N + F_N) v = xb[(size_t)b * XP + (c - H_N)];   // x_0 slice
  A[idx] = v;
}
__global__ void zero_f_k(float* p, int n) {
  int idx = blockIdx.x * 256 + threadIdx.x;
  if (idx < n) p[idx] = 0.f;
}

extern "C" void kernel_launch(void* const* d_in, const int* in_sizes, int n_in,
                              void* d_out, int out_size, void* d_ws, size_t ws_size,
                              hipStream_t stream) {
  const float* x   = (const float*)d_in[0];
  const float* Wg  = (const float*)d_in[1];
  const float* bg  = (const float*)d_in[2];
  const float* Wih = (const float*)d_in[3];
  const float* Whh = (const float*)d_in[4];
  const float* bih = (const float*)d_in[5];
  const float* bhh = (const float*)d_in[6];
  const float* fcW = (const float*)d_in[7];
  const float* fcb = (const float*)d_in[8];
  const float* W1  = (const float*)d_in[9];
  const float* b1  = (const float*)d_in[10];
  const float* W2  = (const float*)d_in[11];
  const float* b2  = (const float*)d_in[12];
  float* out = (float*)d_out;

  char* p = (char*)d_ws;
  auto take = [&](size_t bytes) { void* q = (void*)p; p += (bytes + 255) & ~(size_t)255; return q; };
  u16*   xb   = (u16*)  take((size_t)B_N * XP * 2);            // x in bf16, K-padded
  u16*   Wc   = (u16*)  take((size_t)ER_N * G4H * KA * 2);     // [Whh|Wih|0] bf16
  float* brec = (float*)take((size_t)ER_N * G4H * 4);          // bih+bhh
  u16*   fcWb = (u16*)  take((size_t)ER_N * OUT_N * H_N * 2);
  u16*   W1b  = (u16*)  take((size_t)ES_N * H_N * XP * 2);
  u16*   W2b  = (u16*)  take((size_t)ES_N * OUT_N * H_N * 2);
  u16*   Abuf = (u16*)  take((size_t)ER_N * B_N * KA * 2);     // [h_t | x_t | 0] bf16
  float* Cst  = (float*)take((size_t)ER_N * B_N * H_N * 4);    // c state f32
  u16*   Gts  = (u16*)  take((size_t)ER_N * B_N * G4H * 2);    // gates bf16
  u16*   H1   = (u16*)  take((size_t)ES_N * B_N * H_N * 2);
  float* Ob   = (float*)take((size_t)E_N * B_N * OUT_N * 4);   // expert outputs f32
  float* Wgt  = (float*)take((size_t)B_N * E_N * 4);

  dim3 blk(256);
  prep_x_k   <<<CDIV(B_N * XP, 256),         blk, 0, stream>>>(x, xb);
  prep_wcat_k<<<CDIV(ER_N * G4H * KA, 256),  blk, 0, stream>>>(Whh, Wih, Wc);
  prep_brec_k<<<CDIV(ER_N * G4H, 256),       blk, 0, stream>>>(bih, bhh, brec);
  cvt_k      <<<CDIV(ER_N * OUT_N * H_N, 256), blk, 0, stream>>>(fcW, fcWb, ER_N * OUT_N * H_N);
  prep_w1_k  <<<CDIV(ES_N * H_N * XP, 256),  blk, 0, stream>>>(W1, W1b);
  cvt_k      <<<CDIV(ES_N * OUT_N * H_N, 256), blk, 0, stream>>>(W2, W2b, ES_N * OUT_N * H_N);
  init_A_k   <<<CDIV(ER_N * B_N * KA, 256),  blk, 0, stream>>>(Abuf, xb);
  zero_f_k   <<<CDIV(ER_N * B_N * H_N, 256), blk, 0, stream>>>(Cst, ER_N * B_N * H_N);
  gate_k     <<<B_N / 4,                     blk, 0, stream>>>(x, Wg, bg, Wgt);

  // ---- LSTM recurrence: 28 sequential (GEMM + cell) pairs ----
  for (int t = 0; t < T_N; ++t) {
    gemm_bt<0, 1><<<dim3(G4H / 128, B_N / 128, ER_N), blk, 0, stream>>>(
        Abuf, KA, (long)B_N * KA,
        Wc,   KA, (long)G4H * KA,
        brec, G4H,
        (void*)Gts, G4H, (long)B_N * G4H, KA);
    lstm_cell<<<CDIV(ER_N * B_N * H_N, 256), blk, 0, stream>>>(Gts, Cst, Abuf, xb, t);
  }

  // ---- fc on h_last (Abuf cols 0..511) -> Ob[0..3] ----
  gemm_bt<0, 0><<<dim3(OUT_N / 128, B_N / 128, ER_N), blk, 0, stream>>>(
      Abuf, KA, (long)B_N * KA,
      fcWb, H_N, (long)OUT_N * H_N,
      fcb, OUT_N,
      (void*)Ob, OUT_N, (long)B_N * OUT_N, H_N);

  // ---- simple experts: h1 = relu(x@W1^T + b1); out = h1@W2^T + b2 -> Ob[4..7] ----
  gemm_bt<1, 1><<<dim3(H_N / 128, B_N / 128, ES_N), blk, 0, stream>>>(
      xb, XP, 0L,
      W1b, XP, (long)H_N * XP,
      b1, H_N,
      (void*)H1, H_N, (long)B_N * H_N, XP);
  gemm_bt<0, 0><<<dim3(OUT_N / 128, B_N / 128, ES_N), blk, 0, stream>>>(
      H1, H_N, (long)B_N * H_N,
      W2b, H_N, (long)OUT_N * H_N,
      b2, OUT_N,
      (void*)(Ob + (size_t)ER_N * B_N * OUT_N), OUT_N, (long)B_N * OUT_N, H_N);

  combine_k<<<CDIV(B_N * OUT_N, 256), blk, 0, stream>>>(Ob, Wgt, out);
}

// Round 2
// 1262.513 us; speedup vs baseline: 1.1512x; 1.1512x over previous
//
#include <hip/hip_runtime.h>
#include <stdint.h>

#define CDIV(a,b) (((a)+(b)-1)/(b))

typedef unsigned short u16;
using bf16x8  = __attribute__((ext_vector_type(8))) short;
using floatx4 = __attribute__((ext_vector_type(4))) float;

constexpr int B_N   = 2048;   // batch
constexpr int IN_N  = 784;
constexpr int H_N   = 512;
constexpr int OUT_N = 512;
constexpr int E_N   = 8;
constexpr int ER_N  = 4;      // recurrent experts
constexpr int ES_N  = 4;      // simple experts
constexpr int T_N   = 28;
constexpr int F_N   = 28;
constexpr int G4H   = 2048;   // 4*H
constexpr int KA    = 544;    // 512 (h) + 28 (x_t) + 4 pad  -> mult of 32
constexpr int XP    = 800;    // 784 padded to mult of 32

__device__ __forceinline__ u16 f2bf(float f) {
  union { float f; uint32_t u; } v; v.f = f;
  uint32_t r = v.u + 0x7fffu + ((v.u >> 16) & 1u);   // RNE
  return (u16)(r >> 16);
}
__device__ __forceinline__ float bf2f(u16 u) {
  union { uint32_t u; float f; } v; v.u = ((uint32_t)u) << 16;
  return v.f;
}
__device__ __forceinline__ float sigm(float x)  { return 1.f / (1.f + __expf(-x)); }
__device__ __forceinline__ float tanhf_(float x){ return 1.f - 2.f / (__expf(2.f * x) + 1.f); }

// async global->LDS, 16B per lane. LDS dest = wave-uniform base + lane*16.
__device__ __forceinline__ void async16(const void* g, void* l) {
  __builtin_amdgcn_global_load_lds(
      (__attribute__((address_space(1))) void*)g,
      (__attribute__((address_space(3))) void*)l, 16, 0, 0);
}

// ---------------- generic GEMM: C[z] = A[z] @ B[z]^T + bias[z], optional relu, out bf16/f32 ---
template<int RELU, int OBF>
__global__ __launch_bounds__(256, 2)
void gemm_bt(const u16* __restrict__ A, int lda, long sAz,
             const u16* __restrict__ Bw, int ldb, long sBz,
             const float* __restrict__ bias, int sBiz,
             void* __restrict__ Cv, int ldc, long sCz,
             int K)
{
  __shared__ __align__(16) u16 As[128 * 32];
  __shared__ __align__(16) u16 Bs[128 * 32];
  const int tid  = threadIdx.x;
  const int lane = tid & 63;
  const int wave = tid >> 6;
  const int m0 = blockIdx.y * 128;
  const int n0 = blockIdx.x * 128;
  const int z  = blockIdx.z;
  const u16* Ab = A  + (size_t)z * sAz;
  const u16* Bb = Bw + (size_t)z * sBz;

  const int wm   = (wave & 1) * 64;
  const int wn   = (wave >> 1) * 64;
  const int lm   = lane & 15;
  const int quad = lane >> 4;

  const int s0 = wave * 64 + lane;
  const int r0 = s0 >> 2, c0 = (s0 & 3) * 8;
  const int s1 = s0 + 256;
  const int r1 = s1 >> 2, c1 = (s1 & 3) * 8;

  floatx4 acc[4][4] = {};

  for (int k0 = 0; k0 < K; k0 += 32) {
    async16(Ab + (size_t)(m0 + r0) * lda + (k0 + c0), As + wave * 512);
    async16(Ab + (size_t)(m0 + r1) * lda + (k0 + c1), As + 2048 + wave * 512);
    async16(Bb + (size_t)(n0 + r0) * ldb + (k0 + c0), Bs + wave * 512);
    async16(Bb + (size_t)(n0 + r1) * ldb + (k0 + c1), Bs + 2048 + wave * 512);
    __syncthreads();
    bf16x8 af[4], bf_[4];
#pragma unroll
    for (int i = 0; i < 4; ++i)
      af[i] = *(const bf16x8*)&As[(wm + i * 16 + lm) * 32 + quad * 8];
#pragma unroll
    for (int j = 0; j < 4; ++j)
      bf_[j] = *(const bf16x8*)&Bs[(wn + j * 16 + lm) * 32 + quad * 8];
#pragma unroll
    for (int i = 0; i < 4; ++i)
#pragma unroll
      for (int j = 0; j < 4; ++j)
        acc[i][j] = __builtin_amdgcn_mfma_f32_16x16x32_bf16(af[i], bf_[j], acc[i][j], 0, 0, 0);
    __syncthreads();
  }

  float bj[4];
#pragma unroll
  for (int j = 0; j < 4; ++j)
    bj[j] = bias ? bias[z * sBiz + n0 + wn + j * 16 + lm] : 0.f;

  // D layout (verified m89): col = lane&15, row = quad*4 + r
#pragma unroll
  for (int i = 0; i < 4; ++i) {
#pragma unroll
    for (int r = 0; r < 4; ++r) {
      int m = m0 + wm + i * 16 + quad * 4 + r;
      size_t row = (size_t)z * sCz + (size_t)m * ldc;
#pragma unroll
      for (int j = 0; j < 4; ++j) {
        int n = n0 + wn + j * 16 + lm;
        float v = acc[i][j][r] + bj[j];
        if (RELU) v = fmaxf(v, 0.f);
        if (OBF) ((u16*)Cv)[row + n] = f2bf(v);
        else     ((float*)Cv)[row + n] = v;
      }
    }
  }
}

// ---------------- fused LSTM step: gates GEMM + cell in epilogue -------------------
// Weight Wc rows are PERMUTED: row n holds gate=(n>>4)&3, h=(n>>6)*16+(n&15).
// So lane's j=0..3 fragments are (i,f,g,o) pre-activations of one (m, h) pair.
// Reads Ain = [h_t | x_t | 0] (KA cols), writes h_{t+1} (bf16) and x_{t+1} slice
// into Aout (double buffer -> no intra-launch race), c state fp32 in Cst.
__global__ __launch_bounds__(256, 2)
void gemm_lstm(const u16* __restrict__ Ain, const u16* __restrict__ Wc,
               const float* __restrict__ bperm, float* __restrict__ Cst,
               u16* __restrict__ Aout, const u16* __restrict__ xb, int t)
{
  __shared__ __align__(16) u16 As[128 * 32];
  __shared__ __align__(16) u16 Bs[128 * 32];
  const int tid  = threadIdx.x;
  const int lane = tid & 63;
  const int wave = tid >> 6;
  const int m0 = blockIdx.y * 128;
  const int n0 = blockIdx.x * 128;
  const int z  = blockIdx.z;
  const u16* Ab = Ain + (size_t)z * (B_N * KA);
  const u16* Bb = Wc  + (size_t)z * (G4H * KA);

  const int wm   = (wave & 1) * 64;
  const int wn   = (wave >> 1) * 64;
  const int lm   = lane & 15;
  const int quad = lane >> 4;

  const int s0 = wave * 64 + lane;
  const int r0 = s0 >> 2, c0 = (s0 & 3) * 8;
  const int s1 = s0 + 256;
  const int r1 = s1 >> 2, c1 = (s1 & 3) * 8;

  floatx4 acc[4][4] = {};

  for (int k0 = 0; k0 < KA; k0 += 32) {
    async16(Ab + (size_t)(m0 + r0) * KA + (k0 + c0), As + wave * 512);
    async16(Ab + (size_t)(m0 + r1) * KA + (k0 + c1), As + 2048 + wave * 512);
    async16(Bb + (size_t)(n0 + r0) * KA + (k0 + c0), Bs + wave * 512);
    async16(Bb + (size_t)(n0 + r1) * KA + (k0 + c1), Bs + 2048 + wave * 512);
    __syncthreads();
    bf16x8 af[4], bf_[4];
#pragma unroll
    for (int i = 0; i < 4; ++i)
      af[i] = *(const bf16x8*)&As[(wm + i * 16 + lm) * 32 + quad * 8];
#pragma unroll
    for (int j = 0; j < 4; ++j)
      bf_[j] = *(const bf16x8*)&Bs[(wn + j * 16 + lm) * 32 + quad * 8];
#pragma unroll
    for (int i = 0; i < 4; ++i)
#pragma unroll
      for (int j = 0; j < 4; ++j)
        acc[i][j] = __builtin_amdgcn_mfma_f32_16x16x32_bf16(af[i], bf_[j], acc[i][j], 0, 0, 0);
    __syncthreads();
  }

  float bj[4];
#pragma unroll
  for (int j = 0; j < 4; ++j)
    bj[j] = bperm[z * G4H + n0 + wn + j * 16 + lm];

  const int hcol = ((n0 + wn) >> 6) * 16 + lm;   // 0..511, this lane's h index

#pragma unroll
  for (int i = 0; i < 4; ++i) {
#pragma unroll
    for (int r = 0; r < 4; ++r) {
      int m = m0 + wm + i * 16 + quad * 4 + r;
      float pi = acc[i][0][r] + bj[0];
      float pf = acc[i][1][r] + bj[1];
      float pg = acc[i][2][r] + bj[2];
      float po = acc[i][3][r] + bj[3];
      size_t cidx = ((size_t)(z * B_N + m)) * H_N + hcol;
      float c = sigm(pf) * Cst[cidx] + sigm(pi) * tanhf_(pg);
      Cst[cidx] = c;
      Aout[((size_t)(z * B_N + m)) * KA + hcol] = f2bf(sigm(po) * tanhf_(c));
    }
  }

  // stage x_{t+1} into the write buffer (one block column does it)
  if (blockIdx.x == 0 && t + 1 < T_N) {
    for (int idx = tid; idx < 128 * F_N; idx += 256) {
      int rr = idx / F_N, cc = idx - rr * F_N;
      int m = m0 + rr;
      Aout[((size_t)(z * B_N + m)) * KA + H_N + cc] =
          xb[(size_t)m * XP + (t + 1) * F_N + cc];
    }
  }
}

// ---------------- gate: softmax(scores/e), top-5, renormalize. one wave per row. ----
__global__ __launch_bounds__(256)
void gate_k(const float* __restrict__ x, const float* __restrict__ Wg,
            const float* __restrict__ bg, float* __restrict__ Wt)
{
  int lane = threadIdx.x & 63;
  int row  = blockIdx.x * 4 + (threadIdx.x >> 6);
  float ps[E_N];
#pragma unroll
  for (int e = 0; e < E_N; ++e) ps[e] = 0.f;
  const float* xr = x + (size_t)row * IN_N;
  for (int k = lane; k < IN_N; k += 64) {
    float xv = xr[k];
#pragma unroll
    for (int e = 0; e < E_N; ++e) ps[e] += xv * Wg[e * IN_N + k];
  }
#pragma unroll
  for (int e = 0; e < E_N; ++e) {
#pragma unroll
    for (int off = 32; off >= 1; off >>= 1) ps[e] += __shfl_down(ps[e], off);
  }
  if (lane == 0) {
    float s[E_N], mx = -1e30f;
#pragma unroll
    for (int e = 0; e < E_N; ++e) { s[e] = (ps[e] + bg[e]) * 0.36787944117144233f; mx = fmaxf(mx, s[e]); }
    float pr[E_N], sum = 0.f;
#pragma unroll
    for (int e = 0; e < E_N; ++e) { pr[e] = __expf(s[e] - mx); sum += pr[e]; }
    float inv = 1.f / sum;
#pragma unroll
    for (int e = 0; e < E_N; ++e) pr[e] *= inv;
    unsigned used = 0; float wsum = 0.f;
    for (int k = 0; k < 5; ++k) {            // K = 5 active
      int am = -1; float bv = -1.f;
      for (int e = 0; e < E_N; ++e)
        if (!((used >> e) & 1) && pr[e] > bv) { bv = pr[e]; am = e; }
      used |= 1u << am; wsum += pr[am];
    }
    float winv = 1.f / (wsum + 1e-8f);
    for (int e = 0; e < E_N; ++e)
      Wt[row * E_N + e] = ((used >> e) & 1) ? pr[e] * winv : 0.f;
  }
}

// ---------------- combine: out[b,o] = sum_e w[b,e]*O[e,b,o] ----
__global__ __launch_bounds__(256)
void combine_k(const float* __restrict__ O, const float* __restrict__ Wt, float* __restrict__ out)
{
  int idx = blockIdx.x * 256 + threadIdx.x;
  if (idx >= B_N * OUT_N) return;
  int b = idx / OUT_N;
  float a = 0.f;
#pragma unroll
  for (int e = 0; e < E_N; ++e)
    a += Wt[b * E_N + e] * O[(size_t)e * B_N * OUT_N + idx];
  out[idx] = a;
}

// ---------------- prep kernels ----
__global__ void prep_x_k(const float* __restrict__ x, u16* __restrict__ xb) {
  int idx = blockIdx.x * 256 + threadIdx.x;
  if (idx >= B_N * XP) return;
  int k = idx % XP, b = idx / XP;
  xb[idx] = f2bf(k < IN_N ? x[(size_t)b * IN_N + k] : 0.f);
}
// permuted weight: out row nr holds gate=(nr>>4)&3, h=(nr>>6)*16+(nr&15)
__global__ void prep_wcat_k(const float* __restrict__ Whh, const float* __restrict__ Wih,
                            u16* __restrict__ Wc) {
  int idx = blockIdx.x * 256 + threadIdx.x;
  if (idx >= ER_N * G4H * KA) return;
  int c = idx % KA; int nr = (idx / KA) % G4H; int e = idx / (KA * G4H);
  int h = ((nr >> 6) << 4) + (nr & 15);
  int gate = (nr >> 4) & 3;
  int g = gate * H_N + h;                       // original PyTorch gate row
  float v = 0.f;
  if (c < H_N)             v = Whh[((size_t)(e * G4H + g)) * H_N + c];
  else if (c < H_N + F_N)  v = Wih[((size_t)(e * G4H + g)) * F_N + (c - H_N)];
  Wc[idx] = f2bf(v);
}
__global__ void prep_brec_k(const float* __restrict__ bih, const float* __restrict__ bhh,
                            float* __restrict__ o) {
  int idx = blockIdx.x * 256 + threadIdx.x;
  if (idx >= ER_N * G4H) return;
  int nr = idx % G4H; int e = idx / G4H;
  int h = ((nr >> 6) << 4) + (nr & 15);
  int gate = (nr >> 4) & 3;
  int g = e * G4H + gate * H_N + h;
  o[idx] = bih[g] + bhh[g];
}
__global__ void cvt_k(const float* __restrict__ in, u16* __restrict__ o, int n) {
  int idx = blockIdx.x * 256 + threadIdx.x;
  if (idx < n) o[idx] = f2bf(in[idx]);
}
__global__ void prep_w1_k(const float* __restrict__ W1, u16* __restrict__ o) {
  int idx = blockIdx.x * 256 + threadIdx.x;
  if (idx >= ES_N * H_N * XP) return;
  int k = idx % XP; int r = idx / XP;
  o[idx] = f2bf(k < IN_N ? W1[(size_t)r * IN_N + k] : 0.f);
}
// A0: [h0=0 | x_0 | 0] ; A1: all zero (x written per step, pad never touched)
__global__ void init_A_k(u16* __restrict__ A0, u16* __restrict__ A1, const u16* __restrict__ xb) {
  int idx = blockIdx.x * 256 + threadIdx.x;
  if (idx >= ER_N * B_N * KA) return;
  int c = idx % KA; int b = (idx / KA) % B_N;
  u16 v = 0;
  if (c >= H_N && c < H_N + F_N) v = xb[(size_t)b * XP + (c - H_N)];   // x_0 slice
  A0[idx] = v;
  A1[idx] = 0;
}
__global__ void zero_f_k(float* p, int n) {
  int idx = blockIdx.x * 256 + threadIdx.x;
  if (idx < n) p[idx] = 0.f;
}

extern "C" void kernel_launch(void* const* d_in, const int* in_sizes, int n_in,
                              void* d_out, int out_size, void* d_ws, size_t ws_size,
                              hipStream_t stream) {
  const float* x   = (const float*)d_in[0];
  const float* Wg  = (const float*)d_in[1];
  const float* bg  = (const float*)d_in[2];
  const float* Wih = (const float*)d_in[3];
  const float* Whh = (const float*)d_in[4];
  const float* bih = (const float*)d_in[5];
  const float* bhh = (const float*)d_in[6];
  const float* fcW = (const float*)d_in[7];
  const float* fcb = (const float*)d_in[8];
  const float* W1  = (const float*)d_in[9];
  const float* b1  = (const float*)d_in[10];
  const float* W2  = (const float*)d_in[11];
  const float* b2  = (const float*)d_in[12];
  float* out = (float*)d_out;

  char* p = (char*)d_ws;
  auto take = [&](size_t bytes) { void* q = (void*)p; p += (bytes + 255) & ~(size_t)255; return q; };
  u16*   xb   = (u16*)  take((size_t)B_N * XP * 2);            // x in bf16, padded
  u16*   Wc   = (u16*)  take((size_t)ER_N * G4H * KA * 2);     // permuted [Whh|Wih|0] bf16
  float* brec = (float*)take((size_t)ER_N * G4H * 4);          // permuted bih+bhh
  u16*   fcWb = (u16*)  take((size_t)ER_N * OUT_N * H_N * 2);
  u16*   W1b  = (u16*)  take((size_t)ES_N * H_N * XP * 2);
  u16*   W2b  = (u16*)  take((size_t)ES_N * OUT_N * H_N * 2);
  u16*   A0   = (u16*)  take((size_t)ER_N * B_N * KA * 2);     // ping
  u16*   A1   = (u16*)  take((size_t)ER_N * B_N * KA * 2);     // pong
  float* Cst  = (float*)take((size_t)ER_N * B_N * H_N * 4);    // c state f32
  u16*   H1   = (u16*)  take((size_t)ES_N * B_N * H_N * 2);
  float* Ob   = (float*)take((size_t)E_N * B_N * OUT_N * 4);   // expert outputs f32
  float* Wgt  = (float*)take((size_t)B_N * E_N * 4);

  dim3 blk(256);
  prep_x_k   <<<CDIV(B_N * XP, 256),          blk, 0, stream>>>(x, xb);
  prep_wcat_k<<<CDIV(ER_N * G4H * KA, 256),   blk, 0, stream>>>(Whh, Wih, Wc);
  prep_brec_k<<<CDIV(ER_N * G4H, 256),        blk, 0, stream>>>(bih, bhh, brec);
  cvt_k      <<<CDIV(ER_N * OUT_N * H_N, 256), blk, 0, stream>>>(fcW, fcWb, ER_N * OUT_N * H_N);
  prep_w1_k  <<<CDIV(ES_N * H_N * XP, 256),   blk, 0, stream>>>(W1, W1b);
  cvt_k      <<<CDIV(ES_N * OUT_N * H_N, 256), blk, 0, stream>>>(W2, W2b, ES_N * OUT_N * H_N);
  init_A_k   <<<CDIV(ER_N * B_N * KA, 256),   blk, 0, stream>>>(A0, A1, xb);
  zero_f_k   <<<CDIV(ER_N * B_N * H_N, 256),  blk, 0, stream>>>(Cst, ER_N * B_N * H_N);
  gate_k     <<<B_N / 4,                      blk, 0, stream>>>(x, Wg, bg, Wgt);

  // ---- LSTM recurrence: 28 fused GEMM+cell steps, ping-pong A ----
  for (int t = 0; t < T_N; ++t) {
    u16* Ar = (t & 1) ? A1 : A0;
    u16* Aw = (t & 1) ? A0 : A1;
    gemm_lstm<<<dim3(G4H / 128, B_N / 128, ER_N), blk, 0, stream>>>(
        Ar, Wc, brec, Cst, Aw, xb, t);
  }
  u16* Afin = (T_N & 1) ? A1 : A0;   // T=28 even -> final h in A0

  // ---- fc on h_last (cols 0..511 of Afin) -> Ob[0..3] ----
  gemm_bt<0, 0><<<dim3(OUT_N / 128, B_N / 128, ER_N), blk, 0, stream>>>(
      Afin, KA, (long)B_N * KA,
      fcWb, H_N, (long)OUT_N * H_N,
      fcb, OUT_N,
      (void*)Ob, OUT_N, (long)B_N * OUT_N, H_N);

  // ---- simple experts ----
  gemm_bt<1, 1><<<dim3(H_N / 128, B_N / 128, ES_N), blk, 0, stream>>>(
      xb, XP, 0L,
      W1b, XP, (long)H_N * XP,
      b1, H_N,
      (void*)H1, H_N, (long)B_N * H_N, XP);
  gemm_bt<0, 0><<<dim3(OUT_N / 128, B_N / 128, ES_N), blk, 0, stream>>>(
      H1, H_N, (long)B_N * H_N,
      W2b, H_N, (long)OUT_N * H_N,
      b2, OUT_N,
      (void*)(Ob + (size_t)ER_N * B_N * OUT_N), OUT_N, (long)B_N * OUT_N, H_N);

  combine_k<<<CDIV(B_N * OUT_N, 256), blk, 0, stream>>>(Ob, Wgt, out);
}